// Round 6
// baseline (175.785 us; speedup 1.0000x reference)
//
#include <hip/hip_runtime.h>

// B = IN = OUT = 512; T from out_size.
// v_t = P_t @ x^T [OUT,B]; G = x@x^T [B,B]
//   u = k*(M*e^{-t} + a*v);  h = (u>0);  s = (u>0.2)
//   v' = d*v + e*(h@G + bt*colsum(G))
// Round-6: wave-per-row recurrence (64 lanes, lane owns 8 cols), zero barriers;
// incremental h@G via XOR-bit G-row deltas (sign = new h bit), tab full-recompute
// only when >128 bits flip (step 1). Spikes emitted as per-lane bytes (same
// memory image as the word layout; expand kernel unchanged). GEMMs fused into
// one grid-512 launch, KC=64.

#define NN 512
#define KC 64

// ---- Fused prologue GEMMs (NT): blocks 0..255: M=relu(W·x^T+b), V0=P0·x^T (dual)
//      blocks 256..511: G = x·x^T. 32x32 tiles, 256 thr, 2x2 micro, KC=64.
__global__ __launch_bounds__(256) void gemm32_fused_kernel(
    const float* __restrict__ x, const float* __restrict__ W,
    const float* __restrict__ P0, const float* __restrict__ bias,
    float* __restrict__ M, float* __restrict__ V0, float* __restrict__ G)
{
    const int tid = threadIdx.x;
    const int bid = blockIdx.x;
    const bool isG = bid >= 256;
    const int tb = isG ? bid - 256 : bid;
    const bool dual = !isG;

    const float* A1 = isG ? x : W;
    const float* A2 = P0;             // only read when dual
    const float* Bm = x;
    float* D1 = isG ? G : M;

    const int tx = tid & 15;          // cols 2tx, 2tx+1
    const int ty = tid >> 4;          // rows 2ty, 2ty+1
    const int rb = (tb >> 4) << 5;
    const int cb = (tb & 15) << 5;

    __shared__ float A1t[KC][36];
    __shared__ float A2t[KC][36];
    __shared__ float Bt[KC][36];

    float acc1[2][2] = {{0.f, 0.f}, {0.f, 0.f}};
    float acc2[2][2] = {{0.f, 0.f}, {0.f, 0.f}};

    const int lrow = tid >> 3;        // 0..31
    const int lk = (tid & 7) << 2;    // 0,4,...,28

    for (int k0 = 0; k0 < NN; k0 += KC) {
        const float4 a1a = *(const float4*)(A1 + (size_t)(rb + lrow) * NN + k0 + lk);
        const float4 a1b = *(const float4*)(A1 + (size_t)(rb + lrow) * NN + k0 + lk + 32);
        const float4 bva = *(const float4*)(Bm + (size_t)(cb + lrow) * NN + k0 + lk);
        const float4 bvb = *(const float4*)(Bm + (size_t)(cb + lrow) * NN + k0 + lk + 32);
        float4 a2a = make_float4(0.f, 0.f, 0.f, 0.f), a2b = a2a;
        if (dual) {
            a2a = *(const float4*)(A2 + (size_t)(rb + lrow) * NN + k0 + lk);
            a2b = *(const float4*)(A2 + (size_t)(rb + lrow) * NN + k0 + lk + 32);
        }
        __syncthreads();
        A1t[lk + 0][lrow] = a1a.x; A1t[lk + 1][lrow] = a1a.y;
        A1t[lk + 2][lrow] = a1a.z; A1t[lk + 3][lrow] = a1a.w;
        A1t[lk + 32][lrow] = a1b.x; A1t[lk + 33][lrow] = a1b.y;
        A1t[lk + 34][lrow] = a1b.z; A1t[lk + 35][lrow] = a1b.w;
        Bt[lk + 0][lrow] = bva.x; Bt[lk + 1][lrow] = bva.y;
        Bt[lk + 2][lrow] = bva.z; Bt[lk + 3][lrow] = bva.w;
        Bt[lk + 32][lrow] = bvb.x; Bt[lk + 33][lrow] = bvb.y;
        Bt[lk + 34][lrow] = bvb.z; Bt[lk + 35][lrow] = bvb.w;
        if (dual) {
            A2t[lk + 0][lrow] = a2a.x; A2t[lk + 1][lrow] = a2a.y;
            A2t[lk + 2][lrow] = a2a.z; A2t[lk + 3][lrow] = a2a.w;
            A2t[lk + 32][lrow] = a2b.x; A2t[lk + 33][lrow] = a2b.y;
            A2t[lk + 34][lrow] = a2b.z; A2t[lk + 35][lrow] = a2b.w;
        }
        __syncthreads();

#pragma unroll
        for (int k = 0; k < KC; ++k) {
            const float2 av = *(const float2*)&A1t[k][2 * ty];
            const float2 bw = *(const float2*)&Bt[k][2 * tx];
            acc1[0][0] = fmaf(av.x, bw.x, acc1[0][0]);
            acc1[0][1] = fmaf(av.x, bw.y, acc1[0][1]);
            acc1[1][0] = fmaf(av.y, bw.x, acc1[1][0]);
            acc1[1][1] = fmaf(av.y, bw.y, acc1[1][1]);
            if (dual) {
                const float2 cv = *(const float2*)&A2t[k][2 * ty];
                acc2[0][0] = fmaf(cv.x, bw.x, acc2[0][0]);
                acc2[0][1] = fmaf(cv.x, bw.y, acc2[0][1]);
                acc2[1][0] = fmaf(cv.y, bw.x, acc2[1][0]);
                acc2[1][1] = fmaf(cv.y, bw.y, acc2[1][1]);
            }
        }
    }

#pragma unroll
    for (int i = 0; i < 2; ++i) {
        const int r = rb + 2 * ty + i;
        float2 o = make_float2(acc1[i][0], acc1[i][1]);
        if (dual) {
            const float bb = bias[r];
            o.x = fmaxf(o.x + bb, 0.f);
            o.y = fmaxf(o.y + bb, 0.f);
        }
        *(float2*)(D1 + (size_t)r * NN + cb + 2 * tx) = o;
        if (dual) {
            *(float2*)(V0 + (size_t)r * NN + cb + 2 * tx) = make_float2(acc2[i][0], acc2[i][1]);
        }
    }
}

// ---- colsum: 8 blocks x 256 thr
__global__ __launch_bounds__(256) void colsum_kernel(
    const float* __restrict__ G, float* __restrict__ gs)
{
    __shared__ float red[4][64];
    const int tid = threadIdx.x;
    const int c = (blockIdx.x << 6) + (tid & 63);
    const int g = tid >> 6;
    float s = 0.f;
    for (int bp = 128 * g; bp < 128 * g + 128; ++bp) s += G[(size_t)bp * NN + c];
    if (g > 0) red[g][tid & 63] = s;
    __syncthreads();
    if (g == 0) gs[c] = ((s + red[1][tid & 63]) + red[2][tid & 63]) + red[3][tid & 63];
}

// ---- quad table: tab[((idx*128)+q)*512 + c]
__global__ __launch_bounds__(256) void build_table_kernel(
    const float* __restrict__ G, float* __restrict__ tab)
{
    const int q = blockIdx.x;
    const int j = threadIdx.x;
    for (int c = j; c < NN; c += 256) {
        const float g0 = G[(4 * q + 0) * NN + c];
        const float g1 = G[(4 * q + 1) * NN + c];
        const float g2 = G[(4 * q + 2) * NN + c];
        const float g3 = G[(4 * q + 3) * NN + c];
#pragma unroll
        for (int idx = 0; idx < 16; ++idx) {
            float val = 0.f;
            if (idx & 1) val += g0;
            if (idx & 2) val += g1;
            if (idx & 4) val += g2;
            if (idx & 8) val += g3;
            tab[(((size_t)idx * 128 + q) << 9) + c] = val;
        }
    }
}

// ---- Main recurrence: 512 blocks x 64 threads (one wave per row, no barriers).
// Lane owns cols 8l..8l+7. acc = (h@G)[r, own cols], maintained incrementally:
// per step, only flipped h bits contribute +-G[row, own cols]. Full tab rebuild
// when >128 bits flip in a step (step 1 transient).
__global__ __launch_bounds__(64) void snn_wave_kernel(
    const float* __restrict__ M, const float* __restrict__ G,
    const float* __restrict__ tab, const float* __restrict__ V0,
    const float* __restrict__ gs, const float* __restrict__ alpha,
    const float* __restrict__ eta, const float* __restrict__ beta,
    unsigned char* __restrict__ spb, int T)
{
    const int lane = threadIdx.x;
    const int r = blockIdx.x;
    const int c0 = 8 * lane;

    const float a = alpha[0], e = eta[0], bt = beta[0];
    const float kk = 0.2f;
    const float dd = 0.36787944117144233f;   // exp(-1)
    const float Vth = 0.2f;

    float4 vA = *(const float4*)(V0 + (size_t)r * NN + c0);
    float4 vB = *(const float4*)(V0 + (size_t)r * NN + c0 + 4);
    const float4 mA = *(const float4*)(M + (size_t)r * NN + c0);
    const float4 mB = *(const float4*)(M + (size_t)r * NN + c0 + 4);
    const float4 gA = *(const float4*)(gs + c0);
    const float4 gB = *(const float4*)(gs + c0 + 4);
    float4 cgA, cgB;
    cgA.x = e * bt * gA.x; cgA.y = e * bt * gA.y; cgA.z = e * bt * gA.z; cgA.w = e * bt * gA.w;
    cgB.x = e * bt * gB.x; cgB.y = e * bt * gB.y; cgB.z = e * bt * gB.z; cgB.w = e * bt * gB.w;

    float4 accA = make_float4(0.f, 0.f, 0.f, 0.f);
    float4 accB = make_float4(0.f, 0.f, 0.f, 0.f);
    unsigned oldb = 0;                 // h bits for own 8 cols (acc==0 <-> h==0: exact)
    float em = 1.0f;

    unsigned char* sprow = spb + (size_t)r * 64 + lane;

    for (int t = 0; t < T; ++t) {
        float4 uA, uB;
        uA.x = kk * fmaf(a, vA.x, mA.x * em);
        uA.y = kk * fmaf(a, vA.y, mA.y * em);
        uA.z = kk * fmaf(a, vA.z, mA.z * em);
        uA.w = kk * fmaf(a, vA.w, mA.w * em);
        uB.x = kk * fmaf(a, vB.x, mB.x * em);
        uB.y = kk * fmaf(a, vB.y, mB.y * em);
        uB.z = kk * fmaf(a, vB.z, mB.z * em);
        uB.w = kk * fmaf(a, vB.w, mB.w * em);

        const unsigned hn =
            (uA.x > 0.f ? 1u : 0u)  | (uA.y > 0.f ? 2u : 0u)  |
            (uA.z > 0.f ? 4u : 0u)  | (uA.w > 0.f ? 8u : 0u)  |
            (uB.x > 0.f ? 16u : 0u) | (uB.y > 0.f ? 32u : 0u) |
            (uB.z > 0.f ? 64u : 0u) | (uB.w > 0.f ? 128u : 0u);
        const unsigned sn =
            (uA.x > Vth ? 1u : 0u)  | (uA.y > Vth ? 2u : 0u)  |
            (uA.z > Vth ? 4u : 0u)  | (uA.w > Vth ? 8u : 0u)  |
            (uB.x > Vth ? 16u : 0u) | (uB.y > Vth ? 32u : 0u) |
            (uB.z > Vth ? 64u : 0u) | (uB.w > Vth ? 128u : 0u);

        sprow[(size_t)t * (NN * 64)] = (unsigned char)sn;   // bit i of byte lane = col 8*lane+i

        const unsigned xb = hn ^ oldb;
        oldb = hn;
        const unsigned long long anym = __ballot(xb != 0);

        if (anym != 0ull) {
            int nbits = 0;
#pragma unroll
            for (int b = 0; b < 8; ++b)
                nbits += (int)__popcll(__ballot((xb >> b) & 1u));

            if (nbits > 128) {
                // full rebuild from quad table: 128 rows of 2KB
                accA = make_float4(0.f, 0.f, 0.f, 0.f);
                accB = make_float4(0.f, 0.f, 0.f, 0.f);
                for (int s = 0; s < 64; ++s) {
                    const unsigned hb = (unsigned)__shfl((int)hn, s);
                    const unsigned n0 = hb & 15u;
                    const unsigned n1 = (hb >> 4) & 15u;
                    const float* t0 = tab + (((size_t)n0 * 128 + 2 * s) << 9) + c0;
                    const float* t1 = tab + (((size_t)n1 * 128 + 2 * s + 1) << 9) + c0;
                    const float4 p0 = *(const float4*)t0;
                    const float4 p1 = *(const float4*)(t0 + 4);
                    const float4 q0 = *(const float4*)t1;
                    const float4 q1 = *(const float4*)(t1 + 4);
                    accA.x += p0.x + q0.x; accA.y += p0.y + q0.y;
                    accA.z += p0.z + q0.z; accA.w += p0.w + q0.w;
                    accB.x += p1.x + q1.x; accB.y += p1.y + q1.y;
                    accB.z += p1.z + q1.z; accB.w += p1.w + q1.w;
                }
            } else {
                const int pk = (int)(xb | (hn << 8));
                unsigned long long mask = anym;
                while (mask) {
                    const int s = (int)__builtin_ctzll(mask);
                    mask &= mask - 1ull;
                    const unsigned info = (unsigned)__shfl(pk, s);
                    unsigned xs = info & 255u;
                    const unsigned hs = (info >> 8) & 255u;
                    while (xs) {
                        const int b = (int)__builtin_ctz(xs);
                        xs &= xs - 1u;
                        const float* gp = G + ((size_t)(8 * s + b) << 9) + c0;
                        const float4 g0 = *(const float4*)gp;
                        const float4 g1 = *(const float4*)(gp + 4);
                        if ((hs >> b) & 1u) {
                            accA.x += g0.x; accA.y += g0.y; accA.z += g0.z; accA.w += g0.w;
                            accB.x += g1.x; accB.y += g1.y; accB.z += g1.z; accB.w += g1.w;
                        } else {
                            accA.x -= g0.x; accA.y -= g0.y; accA.z -= g0.z; accA.w -= g0.w;
                            accB.x -= g1.x; accB.y -= g1.y; accB.z -= g1.z; accB.w -= g1.w;
                        }
                    }
                }
            }
        }

        vA.x = fmaf(dd, vA.x, fmaf(e, accA.x, cgA.x));
        vA.y = fmaf(dd, vA.y, fmaf(e, accA.y, cgA.y));
        vA.z = fmaf(dd, vA.z, fmaf(e, accA.z, cgA.z));
        vA.w = fmaf(dd, vA.w, fmaf(e, accA.w, cgA.w));
        vB.x = fmaf(dd, vB.x, fmaf(e, accB.x, cgB.x));
        vB.y = fmaf(dd, vB.y, fmaf(e, accB.y, cgB.y));
        vB.z = fmaf(dd, vB.z, fmaf(e, accB.z, cgB.z));
        vB.w = fmaf(dd, vB.w, fmaf(e, accB.w, cgB.w));
        em *= dd;
    }
}

// ---- Expand: out[t][b][o] = bit b of sp[t][o]. Coalesced float4 stores. (unchanged)
__global__ __launch_bounds__(256) void expand_kernel(
    const unsigned* __restrict__ sp, float* __restrict__ out)
{
    const int tid = threadIdx.x;
    const int t = blockIdx.x >> 3;
    const int bt8 = blockIdx.x & 7;

    __shared__ uint2 sh[NN];
    const uint2* spw = (const uint2*)sp;
    sh[tid]       = spw[((size_t)t * NN + tid) * 8 + bt8];
    sh[tid + 256] = spw[((size_t)t * NN + tid + 256) * 8 + bt8];
    __syncthreads();

    const int b = bt8 * 64 + (tid >> 2);
    const int sub = tid & 3;
    const int rw = (tid >> 2) >> 5;
    const int bit = b & 31;
    float* op = out + (size_t)t * (NN * NN) + (size_t)b * NN;

#pragma unroll 4
    for (int i = 0; i < 32; ++i) {
        const int o = sub * 4 + i * 16;
        const uint2 w0 = sh[o];
        const uint2 w1 = sh[o + 1];
        const uint2 w2 = sh[o + 2];
        const uint2 w3 = sh[o + 3];
        float4 f;
        f.x = (float)(((rw ? w0.y : w0.x) >> bit) & 1u);
        f.y = (float)(((rw ? w1.y : w1.x) >> bit) & 1u);
        f.z = (float)(((rw ? w2.y : w2.x) >> bit) & 1u);
        f.w = (float)(((rw ? w3.y : w3.x) >> bit) & 1u);
        *(float4*)(op + o) = f;
    }
}

// ---- Fallback (tiny ws): round-1 kernel, needs only M/G/V0/gs.
__global__ __launch_bounds__(256) void snn_step_kernel(
    const float* __restrict__ M, const float* __restrict__ G,
    const float* __restrict__ V0, const float* __restrict__ gs,
    const float* __restrict__ alpha, const float* __restrict__ eta,
    const float* __restrict__ beta, float* __restrict__ out, int T)
{
    const int j = threadIdx.x;
    const int r0 = blockIdx.x * 2;
    const int c0 = 2 * j;
    const float a = alpha[0], e = eta[0], bt = beta[0];
    const float kk = 0.2f, dd = 0.36787944117144233f, Vth = 0.2f;

    float v00 = V0[r0 * NN + c0];
    float v01 = V0[r0 * NN + c0 + 1];
    float v10 = V0[(r0 + 1) * NN + c0];
    float v11 = V0[(r0 + 1) * NN + c0 + 1];
    const float m00 = M[r0 * NN + c0];
    const float m01 = M[r0 * NN + c0 + 1];
    const float m10 = M[(r0 + 1) * NN + c0];
    const float m11 = M[(r0 + 1) * NN + c0 + 1];
    const float gs0 = gs[c0];
    const float gs1 = gs[c0 + 1];

    __shared__ float2 hp[NN];
    float em = 1.0f;
    const float2* Gcol = (const float2*)G + j;

    for (int t = 0; t < T; ++t) {
        const float u00 = kk * (m00 * em + a * v00);
        const float u01 = kk * (m01 * em + a * v01);
        const float u10 = kk * (m10 * em + a * v10);
        const float u11 = kk * (m11 * em + a * v11);

        float* outp = out + (size_t)t * (NN * NN);
        float2 sA = make_float2(u00 > Vth ? 1.f : 0.f, u10 > Vth ? 1.f : 0.f);
        float2 sB = make_float2(u01 > Vth ? 1.f : 0.f, u11 > Vth ? 1.f : 0.f);
        *(float2*)(outp + (size_t)c0 * NN + r0) = sA;
        *(float2*)(outp + (size_t)(c0 + 1) * NN + r0) = sB;

        hp[c0]     = make_float2(u00 > 0.f ? 1.f : 0.f, u10 > 0.f ? 1.f : 0.f);
        hp[c0 + 1] = make_float2(u01 > 0.f ? 1.f : 0.f, u11 > 0.f ? 1.f : 0.f);
        __syncthreads();

        float acc00 = 0.f, acc01 = 0.f, acc10 = 0.f, acc11 = 0.f;
#pragma unroll 8
        for (int bp = 0; bp < NN; ++bp) {
            float2 h = hp[bp];
            float2 g = Gcol[(size_t)bp * 256];
            acc00 = fmaf(h.x, g.x, acc00);
            acc01 = fmaf(h.x, g.y, acc01);
            acc10 = fmaf(h.y, g.x, acc10);
            acc11 = fmaf(h.y, g.y, acc11);
        }

        v00 = dd * v00 + e * (acc00 + bt * gs0);
        v01 = dd * v01 + e * (acc01 + bt * gs1);
        v10 = dd * v10 + e * (acc10 + bt * gs0);
        v11 = dd * v11 + e * (acc11 + bt * gs1);
        em *= dd;
        __syncthreads();
    }
}

extern "C" void kernel_launch(void* const* d_in, const int* in_sizes, int n_in,
                              void* d_out, int out_size, void* d_ws, size_t ws_size,
                              hipStream_t stream)
{
    const float* x     = (const float*)d_in[0];
    const float* W     = (const float*)d_in[1];
    const float* bias  = (const float*)d_in[2];
    const float* alpha = (const float*)d_in[3];
    const float* eta   = (const float*)d_in[4];
    const float* beta  = (const float*)d_in[5];
    const float* P0    = (const float*)d_in[6];
    (void)in_sizes; (void)n_in;

    const int T = out_size / (NN * NN);

    float* ws  = (float*)d_ws;
    float* M   = ws;                            // [512,512]
    float* G   = ws + NN * NN;                  // [512,512]
    float* V0  = ws + 2 * NN * NN;              // [512,512]
    float* gsv = ws + 3 * NN * NN;              // [512]
    float* tab = ws + 3 * NN * NN + NN;         // [16][128][512] = 4 MB
    unsigned* sp = (unsigned*)(tab + (size_t)16 * 128 * 512);  // [T][512][16] words

    const size_t need_sp = ((size_t)3 * NN * NN + NN + (size_t)16 * 128 * 512
                            + (size_t)T * NN * 16) * 4;

    hipLaunchKernelGGL(gemm32_fused_kernel, dim3(512), dim3(256), 0, stream,
                       x, W, P0, bias, M, V0, G);
    hipLaunchKernelGGL(colsum_kernel, dim3(8), dim3(256), 0, stream, G, gsv);

    if (ws_size >= need_sp) {
        hipLaunchKernelGGL(build_table_kernel, dim3(128), dim3(256), 0, stream, G, tab);
        hipLaunchKernelGGL(snn_wave_kernel, dim3(NN), dim3(64), 0, stream,
                           M, G, tab, V0, gsv, alpha, eta, beta,
                           (unsigned char*)sp, T);
        hipLaunchKernelGGL(expand_kernel, dim3(T * 8), dim3(256), 0, stream,
                           sp, (float*)d_out);
    } else {
        hipLaunchKernelGGL(snn_step_kernel, dim3(256), dim3(256), 0, stream,
                           M, G, V0, gsv, alpha, eta, beta, (float*)d_out, T);
    }
}

// Round 7
// 152.762 us; speedup vs baseline: 1.1507x; 1.1507x over previous
//
#include <hip/hip_runtime.h>

// B = IN = OUT = 512; T from out_size.
// v_t = P_t @ x^T [OUT,B]; G = x@x^T [B,B]
//   u = k*(M*e^{-t} + a*v);  h = (u>0);  s = (u>0.2)
//   v' = d*v + e*(h@G + bt*colsum(G))
// Round-7: step kernel = 512 blocks x 512 thr; thread owns ONE column (c=tid),
// so acc/v are scalars and no cross-wave reduction exists. Per step: 1 ballot
// per wave -> LDS mask (double-buffered) -> ONE barrier. Frozen steps read one
// 8B flag word and skip. Transient: bit-level deltas +-tab[1<<(row&3)][row>>2]
// (== G[row], exact); full rebuild from quad table when >128 bits flip.
// Prologue: split-K GEMMs (grid 1024, 4 blocks/CU); M/V0 combined in step
// kernel, G1+G2 combined in fused tab+colsum prep kernel. sp aliases G1/G2.

#define NN 512
#define KC 64

// ---- Split-K prologue GEMMs (NT), grid 1024:
//  bid<512:  dual  kh=bid>>8, tile=bid&255:  Mkh = W·x^T (raw), V0kh = P0·x^T (raw)
//  bid>=512: G     kh,tile likewise:         Gkh = x·x^T (raw)
// K range [256*kh, 256*kh+256). 32x32 tiles, 256 thr, 2x2 micro.
__global__ __launch_bounds__(256) void gemm_split_kernel(
    const float* __restrict__ x, const float* __restrict__ W,
    const float* __restrict__ P0,
    float* __restrict__ M1, float* __restrict__ M2,
    float* __restrict__ V01, float* __restrict__ V02,
    float* __restrict__ G1, float* __restrict__ G2)
{
    const int tid = threadIdx.x;
    const int bid = blockIdx.x;
    const bool isG = bid >= 512;
    const int b2 = isG ? bid - 512 : bid;
    const int kh = b2 >> 8;
    const int tb = b2 & 255;
    const int kbase = kh << 8;
    const bool dual = !isG;

    const float* A1 = isG ? x : W;
    const float* Bm = x;
    float* D1 = isG ? (kh ? G2 : G1) : (kh ? M2 : M1);
    float* D2 = kh ? V02 : V01;

    const int tx = tid & 15;          // cols 2tx, 2tx+1
    const int ty = tid >> 4;          // rows 2ty, 2ty+1
    const int rb = (tb >> 4) << 5;
    const int cb = (tb & 15) << 5;

    __shared__ float A1t[KC][36];
    __shared__ float A2t[KC][36];
    __shared__ float Bt[KC][36];

    float acc1[2][2] = {{0.f, 0.f}, {0.f, 0.f}};
    float acc2[2][2] = {{0.f, 0.f}, {0.f, 0.f}};

    const int lrow = tid >> 3;        // 0..31
    const int lk = (tid & 7) << 2;    // 0,4,...,28

    for (int k0 = kbase; k0 < kbase + 256; k0 += KC) {
        const float4 a1a = *(const float4*)(A1 + (size_t)(rb + lrow) * NN + k0 + lk);
        const float4 a1b = *(const float4*)(A1 + (size_t)(rb + lrow) * NN + k0 + lk + 32);
        const float4 bva = *(const float4*)(Bm + (size_t)(cb + lrow) * NN + k0 + lk);
        const float4 bvb = *(const float4*)(Bm + (size_t)(cb + lrow) * NN + k0 + lk + 32);
        float4 a2a = make_float4(0.f, 0.f, 0.f, 0.f), a2b = a2a;
        if (dual) {
            a2a = *(const float4*)(P0 + (size_t)(rb + lrow) * NN + k0 + lk);
            a2b = *(const float4*)(P0 + (size_t)(rb + lrow) * NN + k0 + lk + 32);
        }
        __syncthreads();
        A1t[lk + 0][lrow] = a1a.x; A1t[lk + 1][lrow] = a1a.y;
        A1t[lk + 2][lrow] = a1a.z; A1t[lk + 3][lrow] = a1a.w;
        A1t[lk + 32][lrow] = a1b.x; A1t[lk + 33][lrow] = a1b.y;
        A1t[lk + 34][lrow] = a1b.z; A1t[lk + 35][lrow] = a1b.w;
        Bt[lk + 0][lrow] = bva.x; Bt[lk + 1][lrow] = bva.y;
        Bt[lk + 2][lrow] = bva.z; Bt[lk + 3][lrow] = bva.w;
        Bt[lk + 32][lrow] = bvb.x; Bt[lk + 33][lrow] = bvb.y;
        Bt[lk + 34][lrow] = bvb.z; Bt[lk + 35][lrow] = bvb.w;
        if (dual) {
            A2t[lk + 0][lrow] = a2a.x; A2t[lk + 1][lrow] = a2a.y;
            A2t[lk + 2][lrow] = a2a.z; A2t[lk + 3][lrow] = a2a.w;
            A2t[lk + 32][lrow] = a2b.x; A2t[lk + 33][lrow] = a2b.y;
            A2t[lk + 34][lrow] = a2b.z; A2t[lk + 35][lrow] = a2b.w;
        }
        __syncthreads();

#pragma unroll
        for (int k = 0; k < KC; ++k) {
            const float2 av = *(const float2*)&A1t[k][2 * ty];
            const float2 bw = *(const float2*)&Bt[k][2 * tx];
            acc1[0][0] = fmaf(av.x, bw.x, acc1[0][0]);
            acc1[0][1] = fmaf(av.x, bw.y, acc1[0][1]);
            acc1[1][0] = fmaf(av.y, bw.x, acc1[1][0]);
            acc1[1][1] = fmaf(av.y, bw.y, acc1[1][1]);
            if (dual) {
                const float2 cv = *(const float2*)&A2t[k][2 * ty];
                acc2[0][0] = fmaf(cv.x, bw.x, acc2[0][0]);
                acc2[0][1] = fmaf(cv.x, bw.y, acc2[0][1]);
                acc2[1][0] = fmaf(cv.y, bw.x, acc2[1][0]);
                acc2[1][1] = fmaf(cv.y, bw.y, acc2[1][1]);
            }
        }
    }

#pragma unroll
    for (int i = 0; i < 2; ++i) {
        const int r = rb + 2 * ty + i;
        *(float2*)(D1 + (size_t)r * NN + cb + 2 * tx) = make_float2(acc1[i][0], acc1[i][1]);
        if (dual) {
            *(float2*)(D2 + (size_t)r * NN + cb + 2 * tx) = make_float2(acc2[i][0], acc2[i][1]);
        }
    }
}

// ---- Fused prep: blocks 0..127 build quad table from G1+G2; blocks 128..135 colsum.
// tab[((idx*128)+q)*512 + c] = sum_{i: idx bit i} (G1+G2)[4q+i][c]
__global__ __launch_bounds__(256) void prep_kernel(
    const float* __restrict__ G1, const float* __restrict__ G2,
    float* __restrict__ tab, float* __restrict__ gs)
{
    const int tid = threadIdx.x;
    if (blockIdx.x < 128) {
        const int q = blockIdx.x;
        for (int c = tid; c < NN; c += 256) {
            const float g0 = G1[(4 * q + 0) * NN + c] + G2[(4 * q + 0) * NN + c];
            const float g1 = G1[(4 * q + 1) * NN + c] + G2[(4 * q + 1) * NN + c];
            const float g2 = G1[(4 * q + 2) * NN + c] + G2[(4 * q + 2) * NN + c];
            const float g3 = G1[(4 * q + 3) * NN + c] + G2[(4 * q + 3) * NN + c];
#pragma unroll
            for (int idx = 0; idx < 16; ++idx) {
                float val = 0.f;
                if (idx & 1) val += g0;
                if (idx & 2) val += g1;
                if (idx & 4) val += g2;
                if (idx & 8) val += g3;
                tab[(((size_t)idx * 128 + q) << 9) + c] = val;
            }
        }
    } else {
        __shared__ float red[4][64];
        const int c = ((blockIdx.x - 128) << 6) + (tid & 63);
        const int g = tid >> 6;
        float s = 0.f;
        for (int bp = 128 * g; bp < 128 * g + 128; ++bp)
            s += G1[(size_t)bp * NN + c] + G2[(size_t)bp * NN + c];
        if (g > 0) red[g][tid & 63] = s;
        __syncthreads();
        if (g == 0) gs[c] = ((s + red[1][tid & 63]) + red[2][tid & 63]) + red[3][tid & 63];
    }
}

// ---- Main recurrence: 512 blocks x 512 threads. Thread owns col c = tid.
// Wave w publishes its 64 h-bits via one ballot into LDS; one barrier/step.
// acc (scalar) maintained by bit-level +-tab single-row deltas; full rebuild
// from the quad table when >128 bits flip. All control flow block-uniform.
__global__ __launch_bounds__(512) void snn_bits_kernel(
    const float* __restrict__ M1, const float* __restrict__ M2,
    const float* __restrict__ bias, const float* __restrict__ tab,
    const float* __restrict__ V01, const float* __restrict__ V02,
    const float* __restrict__ gs, const float* __restrict__ alpha,
    const float* __restrict__ eta, const float* __restrict__ beta,
    unsigned* __restrict__ sp, int T)
{
    const int tid = threadIdx.x;
    const int w = tid >> 6;
    const int lane = tid & 63;
    const int r = blockIdx.x;

    __shared__ unsigned long long lmask[2][8];
    __shared__ unsigned long long lflag[2];

    const float a = alpha[0], e = eta[0], bt = beta[0];
    const float kk = 0.2f;
    const float dd = 0.36787944117144233f;   // exp(-1)
    const float Vth = 0.2f;

    const size_t rc = (size_t)r * NN + tid;
    const float m = fmaxf(M1[rc] + M2[rc] + bias[r], 0.f);
    float v = V01[rc] + V02[rc];
    const float cg = e * bt * gs[tid];
    const float* tbc = tab + tid;

    float acc = 0.f;
    unsigned long long o0 = 0, o1 = 0, o2 = 0, o3 = 0, o4 = 0, o5 = 0, o6 = 0, o7 = 0;
    unsigned long long myold = 0;     // own wave's old word (wave-uniform)
    float em = 1.0f;

    for (int t = 0; t < T; ++t) {
        const float u = kk * fmaf(a, v, m * em);
        const unsigned long long hb = __ballot(u > 0.f);
        const unsigned long long sb = __ballot(u > Vth);
        const int p = t & 1;
        if (lane == 0) {
            lmask[p][w] = hb;
            ((unsigned char*)&lflag[p])[w] = (hb != myold) ? (unsigned char)1 : (unsigned char)0;
            // sp words 2w,2w+1 of row: bit l of hb <-> col 64w+l (matches expand layout)
            *(unsigned long long*)(sp + ((size_t)t * NN + r) * 16 + 2 * w) = sb;
        }
        __syncthreads();   // single barrier per step (masks double-buffered)

        if (lflag[p] != 0ull) {
            const unsigned long long n0 = lmask[p][0], n1 = lmask[p][1],
                n2 = lmask[p][2], n3 = lmask[p][3], n4 = lmask[p][4],
                n5 = lmask[p][5], n6 = lmask[p][6], n7 = lmask[p][7];
            const unsigned long long x0 = n0 ^ o0, x1 = n1 ^ o1, x2 = n2 ^ o2,
                x3 = n3 ^ o3, x4 = n4 ^ o4, x5 = n5 ^ o5, x6 = n6 ^ o6, x7 = n7 ^ o7;
            const int nbits = __popcll(x0) + __popcll(x1) + __popcll(x2) + __popcll(x3)
                            + __popcll(x4) + __popcll(x5) + __popcll(x6) + __popcll(x7);

            if (nbits > 128) {
                // full rebuild from quad table: 128 coalesced scalar loads
                float s0 = 0.f, s1 = 0.f, s2 = 0.f, s3 = 0.f;
#define FULLW(i, nw) \
                _Pragma("unroll") \
                for (int j = 0; j < 16; ++j) { \
                    const unsigned idx = (unsigned)((nw >> (4 * j)) & 15ull); \
                    const float gv = tbc[((size_t)(idx * 128u + 16u * i + (unsigned)j)) << 9]; \
                    if ((j & 3) == 0) s0 += gv; else if ((j & 3) == 1) s1 += gv; \
                    else if ((j & 3) == 2) s2 += gv; else s3 += gv; \
                }
                FULLW(0, n0) FULLW(1, n1) FULLW(2, n2) FULLW(3, n3)
                FULLW(4, n4) FULLW(5, n5) FULLW(6, n6) FULLW(7, n7)
                acc = (s0 + s1) + (s2 + s3);
            } else {
                // bit deltas: tab[1<<(row&3)][row>>2][c] == (G1+G2)[row][c] exactly
#define DELTW(i, nw, xw) { \
                unsigned long long d = xw; \
                while (d) { \
                    const int b = __builtin_ctzll(d); d &= d - 1ull; \
                    const float gv = tbc[((size_t)(((1u << (b & 3)) * 128u) + 16u * i + (unsigned)(b >> 2))) << 9]; \
                    acc += ((nw >> b) & 1ull) ? gv : -gv; \
                } }
                DELTW(0, n0, x0) DELTW(1, n1, x1) DELTW(2, n2, x2) DELTW(3, n3, x3)
                DELTW(4, n4, x4) DELTW(5, n5, x5) DELTW(6, n6, x6) DELTW(7, n7, x7)
            }
            o0 = n0; o1 = n1; o2 = n2; o3 = n3; o4 = n4; o5 = n5; o6 = n6; o7 = n7;
            myold = hb;
        }

        v = fmaf(dd, v, fmaf(e, acc, cg));
        em *= dd;
    }
}

// ---- Expand: out[t][b][o] = bit b of sp[t][o]. Coalesced float4 stores.
__global__ __launch_bounds__(256) void expand_kernel(
    const unsigned* __restrict__ sp, float* __restrict__ out)
{
    const int tid = threadIdx.x;
    const int t = blockIdx.x >> 3;
    const int bt8 = blockIdx.x & 7;

    __shared__ uint2 sh[NN];
    const uint2* spw = (const uint2*)sp;
    sh[tid]       = spw[((size_t)t * NN + tid) * 8 + bt8];
    sh[tid + 256] = spw[((size_t)t * NN + tid + 256) * 8 + bt8];
    __syncthreads();

    const int b = bt8 * 64 + (tid >> 2);
    const int sub = tid & 3;
    const int rw = (tid >> 2) >> 5;
    const int bit = b & 31;
    float* op = out + (size_t)t * (NN * NN) + (size_t)b * NN;

#pragma unroll 4
    for (int i = 0; i < 32; ++i) {
        const int o = sub * 4 + i * 16;
        const uint2 w0 = sh[o];
        const uint2 w1 = sh[o + 1];
        const uint2 w2 = sh[o + 2];
        const uint2 w3 = sh[o + 3];
        float4 f;
        f.x = (float)(((rw ? w0.y : w0.x) >> bit) & 1u);
        f.y = (float)(((rw ? w1.y : w1.x) >> bit) & 1u);
        f.z = (float)(((rw ? w2.y : w2.x) >> bit) & 1u);
        f.w = (float)(((rw ? w3.y : w3.x) >> bit) & 1u);
        *(float4*)(op + o) = f;
    }
}

// ================= Fallback path (small ws): round-6 fused gemm + colsum +
// round-1 step kernel (direct strided writes). Needs 3 MB + 2 KB of ws.
__global__ __launch_bounds__(256) void gemm32_fused_kernel(
    const float* __restrict__ x, const float* __restrict__ W,
    const float* __restrict__ P0, const float* __restrict__ bias,
    float* __restrict__ M, float* __restrict__ V0, float* __restrict__ G)
{
    const int tid = threadIdx.x;
    const int bid = blockIdx.x;
    const bool isG = bid >= 256;
    const int tb = isG ? bid - 256 : bid;
    const bool dual = !isG;

    const float* A1 = isG ? x : W;
    const float* Bm = x;
    float* D1 = isG ? G : M;

    const int tx = tid & 15;
    const int ty = tid >> 4;
    const int rb = (tb >> 4) << 5;
    const int cb = (tb & 15) << 5;

    __shared__ float A1t[KC][36];
    __shared__ float A2t[KC][36];
    __shared__ float Bt[KC][36];

    float acc1[2][2] = {{0.f, 0.f}, {0.f, 0.f}};
    float acc2[2][2] = {{0.f, 0.f}, {0.f, 0.f}};

    const int lrow = tid >> 3;
    const int lk = (tid & 7) << 2;

    for (int k0 = 0; k0 < NN; k0 += KC) {
        const float4 a1a = *(const float4*)(A1 + (size_t)(rb + lrow) * NN + k0 + lk);
        const float4 a1b = *(const float4*)(A1 + (size_t)(rb + lrow) * NN + k0 + lk + 32);
        const float4 bva = *(const float4*)(Bm + (size_t)(cb + lrow) * NN + k0 + lk);
        const float4 bvb = *(const float4*)(Bm + (size_t)(cb + lrow) * NN + k0 + lk + 32);
        float4 a2a = make_float4(0.f, 0.f, 0.f, 0.f), a2b = a2a;
        if (dual) {
            a2a = *(const float4*)(P0 + (size_t)(rb + lrow) * NN + k0 + lk);
            a2b = *(const float4*)(P0 + (size_t)(rb + lrow) * NN + k0 + lk + 32);
        }
        __syncthreads();
        A1t[lk + 0][lrow] = a1a.x; A1t[lk + 1][lrow] = a1a.y;
        A1t[lk + 2][lrow] = a1a.z; A1t[lk + 3][lrow] = a1a.w;
        A1t[lk + 32][lrow] = a1b.x; A1t[lk + 33][lrow] = a1b.y;
        A1t[lk + 34][lrow] = a1b.z; A1t[lk + 35][lrow] = a1b.w;
        Bt[lk + 0][lrow] = bva.x; Bt[lk + 1][lrow] = bva.y;
        Bt[lk + 2][lrow] = bva.z; Bt[lk + 3][lrow] = bva.w;
        Bt[lk + 32][lrow] = bvb.x; Bt[lk + 33][lrow] = bvb.y;
        Bt[lk + 34][lrow] = bvb.z; Bt[lk + 35][lrow] = bvb.w;
        if (dual) {
            A2t[lk + 0][lrow] = a2a.x; A2t[lk + 1][lrow] = a2a.y;
            A2t[lk + 2][lrow] = a2a.z; A2t[lk + 3][lrow] = a2a.w;
            A2t[lk + 32][lrow] = a2b.x; A2t[lk + 33][lrow] = a2b.y;
            A2t[lk + 34][lrow] = a2b.z; A2t[lk + 35][lrow] = a2b.w;
        }
        __syncthreads();

#pragma unroll
        for (int k = 0; k < KC; ++k) {
            const float2 av = *(const float2*)&A1t[k][2 * ty];
            const float2 bw = *(const float2*)&Bt[k][2 * tx];
            acc1[0][0] = fmaf(av.x, bw.x, acc1[0][0]);
            acc1[0][1] = fmaf(av.x, bw.y, acc1[0][1]);
            acc1[1][0] = fmaf(av.y, bw.x, acc1[1][0]);
            acc1[1][1] = fmaf(av.y, bw.y, acc1[1][1]);
            if (dual) {
                const float2 cv = *(const float2*)&A2t[k][2 * ty];
                acc2[0][0] = fmaf(cv.x, bw.x, acc2[0][0]);
                acc2[0][1] = fmaf(cv.x, bw.y, acc2[0][1]);
                acc2[1][0] = fmaf(cv.y, bw.x, acc2[1][0]);
                acc2[1][1] = fmaf(cv.y, bw.y, acc2[1][1]);
            }
        }
    }

#pragma unroll
    for (int i = 0; i < 2; ++i) {
        const int r = rb + 2 * ty + i;
        float2 o = make_float2(acc1[i][0], acc1[i][1]);
        if (dual) {
            const float bb = bias[r];
            o.x = fmaxf(o.x + bb, 0.f);
            o.y = fmaxf(o.y + bb, 0.f);
        }
        *(float2*)(D1 + (size_t)r * NN + cb + 2 * tx) = o;
        if (dual) {
            *(float2*)(V0 + (size_t)r * NN + cb + 2 * tx) = make_float2(acc2[i][0], acc2[i][1]);
        }
    }
}

__global__ __launch_bounds__(256) void colsum1_kernel(
    const float* __restrict__ G, float* __restrict__ gs)
{
    __shared__ float red[4][64];
    const int tid = threadIdx.x;
    const int c = (blockIdx.x << 6) + (tid & 63);
    const int g = tid >> 6;
    float s = 0.f;
    for (int bp = 128 * g; bp < 128 * g + 128; ++bp) s += G[(size_t)bp * NN + c];
    if (g > 0) red[g][tid & 63] = s;
    __syncthreads();
    if (g == 0) gs[c] = ((s + red[1][tid & 63]) + red[2][tid & 63]) + red[3][tid & 63];
}

__global__ __launch_bounds__(256) void snn_step_kernel(
    const float* __restrict__ M, const float* __restrict__ G,
    const float* __restrict__ V0, const float* __restrict__ gs,
    const float* __restrict__ alpha, const float* __restrict__ eta,
    const float* __restrict__ beta, float* __restrict__ out, int T)
{
    const int j = threadIdx.x;
    const int r0 = blockIdx.x * 2;
    const int c0 = 2 * j;
    const float a = alpha[0], e = eta[0], bt = beta[0];
    const float kk = 0.2f, dd = 0.36787944117144233f, Vth = 0.2f;

    float v00 = V0[r0 * NN + c0];
    float v01 = V0[r0 * NN + c0 + 1];
    float v10 = V0[(r0 + 1) * NN + c0];
    float v11 = V0[(r0 + 1) * NN + c0 + 1];
    const float m00 = M[r0 * NN + c0];
    const float m01 = M[r0 * NN + c0 + 1];
    const float m10 = M[(r0 + 1) * NN + c0];
    const float m11 = M[(r0 + 1) * NN + c0 + 1];
    const float gs0 = gs[c0];
    const float gs1 = gs[c0 + 1];

    __shared__ float2 hp[NN];
    float em = 1.0f;
    const float2* Gcol = (const float2*)G + j;

    for (int t = 0; t < T; ++t) {
        const float u00 = kk * (m00 * em + a * v00);
        const float u01 = kk * (m01 * em + a * v01);
        const float u10 = kk * (m10 * em + a * v10);
        const float u11 = kk * (m11 * em + a * v11);

        float* outp = out + (size_t)t * (NN * NN);
        float2 sA = make_float2(u00 > Vth ? 1.f : 0.f, u10 > Vth ? 1.f : 0.f);
        float2 sB = make_float2(u01 > Vth ? 1.f : 0.f, u11 > Vth ? 1.f : 0.f);
        *(float2*)(outp + (size_t)c0 * NN + r0) = sA;
        *(float2*)(outp + (size_t)(c0 + 1) * NN + r0) = sB;

        hp[c0]     = make_float2(u00 > 0.f ? 1.f : 0.f, u10 > 0.f ? 1.f : 0.f);
        hp[c0 + 1] = make_float2(u01 > 0.f ? 1.f : 0.f, u11 > 0.f ? 1.f : 0.f);
        __syncthreads();

        float acc00 = 0.f, acc01 = 0.f, acc10 = 0.f, acc11 = 0.f;
#pragma unroll 8
        for (int bp = 0; bp < NN; ++bp) {
            float2 h = hp[bp];
            float2 g = Gcol[(size_t)bp * 256];
            acc00 = fmaf(h.x, g.x, acc00);
            acc01 = fmaf(h.x, g.y, acc01);
            acc10 = fmaf(h.y, g.x, acc10);
            acc11 = fmaf(h.y, g.y, acc11);
        }

        v00 = dd * v00 + e * (acc00 + bt * gs0);
        v01 = dd * v01 + e * (acc01 + bt * gs1);
        v10 = dd * v10 + e * (acc10 + bt * gs0);
        v11 = dd * v11 + e * (acc11 + bt * gs1);
        em *= dd;
        __syncthreads();
    }
}

extern "C" void kernel_launch(void* const* d_in, const int* in_sizes, int n_in,
                              void* d_out, int out_size, void* d_ws, size_t ws_size,
                              hipStream_t stream)
{
    const float* x     = (const float*)d_in[0];
    const float* W     = (const float*)d_in[1];
    const float* bias  = (const float*)d_in[2];
    const float* alpha = (const float*)d_in[3];
    const float* eta   = (const float*)d_in[4];
    const float* beta  = (const float*)d_in[5];
    const float* P0    = (const float*)d_in[6];
    (void)in_sizes; (void)n_in;

    const int T = out_size / (NN * NN);

    float* ws   = (float*)d_ws;
    float* M1   = ws;                          // [512,512] raw (K half 0)
    float* M2   = ws + NN * NN;                // [512,512] raw (K half 1)
    float* V01  = ws + 2 * NN * NN;
    float* V02  = ws + 3 * NN * NN;
    float* gsv  = ws + 4 * NN * NN;            // [512]
    float* tab  = gsv + NN;                    // [16][128][512] = 4 MB
    float* Gbuf = tab + (size_t)16 * 128 * 512;// G1,G2 = 2 MB; sp aliases this
    float* G1   = Gbuf;
    float* G2   = Gbuf + NN * NN;
    unsigned* sp = (unsigned*)Gbuf;            // [T][512][16] words = 2 MB (T=64)

    const size_t spw_bytes = (size_t)T * NN * 16 * 4;
    const size_t gbuf_bytes = (spw_bytes > (size_t)2 * NN * NN * 4)
                              ? spw_bytes : (size_t)2 * NN * NN * 4;
    const size_t need_main = ((size_t)4 * NN * NN + NN + (size_t)16 * 128 * 512) * 4
                             + gbuf_bytes;

    if (ws_size >= need_main) {
        hipLaunchKernelGGL(gemm_split_kernel, dim3(1024), dim3(256), 0, stream,
                           x, W, P0, M1, M2, V01, V02, G1, G2);
        hipLaunchKernelGGL(prep_kernel, dim3(136), dim3(256), 0, stream,
                           G1, G2, tab, gsv);
        hipLaunchKernelGGL(snn_bits_kernel, dim3(NN), dim3(512), 0, stream,
                           M1, M2, bias, tab, V01, V02, gsv, alpha, eta, beta,
                           sp, T);
        hipLaunchKernelGGL(expand_kernel, dim3(T * 8), dim3(256), 0, stream,
                           sp, (float*)d_out);
    } else {
        // legacy small-ws path: M, G, V0, gs
        float* M  = ws;
        float* G  = ws + NN * NN;
        float* V0 = ws + 2 * NN * NN;
        float* gs2 = ws + 3 * NN * NN;
        hipLaunchKernelGGL(gemm32_fused_kernel, dim3(512), dim3(256), 0, stream,
                           x, W, P0, bias, M, V0, G);
        hipLaunchKernelGGL(colsum1_kernel, dim3(8), dim3(256), 0, stream, G, gs2);
        hipLaunchKernelGGL(snn_step_kernel, dim3(256), dim3(256), 0, stream,
                           M, G, V0, gs2, alpha, eta, beta, (float*)d_out, T);
    }
}